// Round 1
// baseline (1792.977 us; speedup 1.0000x reference)
//
#include <hip/hip_runtime.h>

#define T_TOK 8192
#define H_DIM 2048
#define I_DIM 1408
#define N_EXP 8
#define MAX_TILES 264

typedef __attribute__((ext_vector_type(8))) short short8;
typedef __attribute__((ext_vector_type(8))) unsigned short ushort8;
typedef __attribute__((ext_vector_type(4))) float f32x4;

// ---- workspace layout (bytes) ----
// 0      : counts[8]
// 32     : cursor[8]
// 64     : ntiles[1]
// 128    : tile_e[264]
// 1280   : tile_b[264]
// 2432   : tile_r[264]
// 4096   : topk_e[T*2]      (int)
// 69632  : topk_p[T*2]      (float)
// 135168 : pair_tok[16384]  (int)
// 200704 : pair_w[16384]    (float)
// 266240 : Xb  bf16 [T][H]          = 33,554,432 B
// 33820672: G  bf16 [16384][I]      = 46,137,344 B   (ends ~79.96 MB)

__device__ __forceinline__ unsigned short f2bf(float f) {
  unsigned u = __float_as_uint(f);
  u += 0x7fffu + ((u >> 16) & 1u);   // RNE
  return (unsigned short)(u >> 16);
}

// ---------------- router: one wave per token ----------------
__global__ __launch_bounds__(256) void router_kernel(
    const float* __restrict__ X, const float* __restrict__ GW,
    int* __restrict__ topk_e, float* __restrict__ topk_p, int* __restrict__ counts) {
  int wave = threadIdx.x >> 6, lane = threadIdx.x & 63;
  int token = blockIdx.x * 4 + wave;
  const float4* x4 = (const float4*)(X + (size_t)token * H_DIM);
  const float4* g4 = (const float4*)GW;
  float acc[8];
#pragma unroll
  for (int e = 0; e < 8; e++) acc[e] = 0.f;
#pragma unroll
  for (int i = 0; i < 8; i++) {
    float4 xv = x4[lane + i * 64];
#pragma unroll
    for (int e = 0; e < 8; e++) {
      float4 gv = g4[e * 512 + lane + i * 64];
      acc[e] += xv.x * gv.x + xv.y * gv.y + xv.z * gv.z + xv.w * gv.w;
    }
  }
#pragma unroll
  for (int e = 0; e < 8; e++)
    for (int off = 32; off; off >>= 1) acc[e] += __shfl_down(acc[e], off);
  if (lane == 0) {
    int e1 = 0; float l1 = acc[0];
#pragma unroll
    for (int e = 1; e < 8; e++) if (acc[e] > l1) { l1 = acc[e]; e1 = e; }
    int e2 = -1; float l2 = -1e30f;
#pragma unroll
    for (int e = 0; e < 8; e++) if (e != e1 && acc[e] > l2) { l2 = acc[e]; e2 = e; }
    float t = __expf(l2 - l1);            // <= 1
    float p1 = 1.f / (1.f + t);
    float p2 = t / (1.f + t);
    topk_e[token * 2] = e1; topk_e[token * 2 + 1] = e2;
    topk_p[token * 2] = p1; topk_p[token * 2 + 1] = p2;
    atomicAdd(&counts[e1], 1);
    atomicAdd(&counts[e2], 1);
  }
}

// ---------------- setup: scan + tile table (1 thread) ----------------
__global__ void setup_kernel(const int* __restrict__ counts, int* __restrict__ cursor,
                             int* __restrict__ ntiles, int* __restrict__ tile_e,
                             int* __restrict__ tile_b, int* __restrict__ tile_r) {
  int off = 0, nt = 0;
  for (int e = 0; e < N_EXP; e++) {
    cursor[e] = off;
    int n = counts[e];
    for (int t = 0; t * 64 < n; t++) {
      tile_e[nt] = e;
      tile_b[nt] = off + t * 64;
      tile_r[nt] = (n - t * 64) < 64 ? (n - t * 64) : 64;
      nt++;
    }
    off += n;
  }
  *ntiles = nt;
}

// ---------------- scatter pairs ----------------
__global__ void scatter_kernel(const int* __restrict__ topk_e, const float* __restrict__ topk_p,
                               int* __restrict__ cursor, int* __restrict__ pair_tok,
                               float* __restrict__ pair_w) {
  int t = blockIdx.x * 256 + threadIdx.x;
  if (t >= T_TOK) return;
#pragma unroll
  for (int k = 0; k < 2; k++) {
    int e = topk_e[t * 2 + k];
    int pos = atomicAdd(&cursor[e], 1);
    pair_tok[pos] = t;
    pair_w[pos] = topk_p[t * 2 + k];
  }
}

// ---------------- X -> bf16 ----------------
__global__ __launch_bounds__(256) void cvt_kernel(const float* __restrict__ X,
                                                  unsigned short* __restrict__ Xb) {
  int i = blockIdx.x * 256 + threadIdx.x;   // handles 8 elements
  const float4* src = (const float4*)X;
  float4 a = src[2 * i], b = src[2 * i + 1];
  ushort8 v;
  v[0] = f2bf(a.x); v[1] = f2bf(a.y); v[2] = f2bf(a.z); v[3] = f2bf(a.w);
  v[4] = f2bf(b.x); v[5] = f2bf(b.y); v[6] = f2bf(b.z); v[7] = f2bf(b.w);
  *(ushort8*)(Xb + (size_t)i * 8) = v;
}

// ---------------- GEMM1: G = silu(X Wg) * (X Wu), per expert ----------------
__global__ __launch_bounds__(256) void gemm1_kernel(
    const unsigned short* __restrict__ Xb, const float* __restrict__ Wg,
    const float* __restrict__ Wu, const int* __restrict__ ntiles,
    const int* __restrict__ tile_e, const int* __restrict__ tile_b,
    const int* __restrict__ tile_r, const int* __restrict__ pair_tok,
    unsigned short* __restrict__ G) {
  int bx = blockIdx.x;
  if (bx >= *ntiles) return;
  int e = tile_e[bx], mbase = tile_b[bx], rows = tile_r[bx];
  int n0 = blockIdx.y * 64;
  int tid = threadIdx.x, wave = tid >> 6, lane = tid & 63;
  int quad = lane >> 4, c = lane & 15;

  __shared__ __align__(16) unsigned short Bg[64][40];
  __shared__ __align__(16) unsigned short Bu[64][40];

  int mA = wave * 16 + c;
  int rowA = mbase + (mA < rows ? mA : 0);
  const unsigned short* Arow = Xb + (size_t)pair_tok[rowA] * H_DIM;

  f32x4 accg[4], accu[4];
#pragma unroll
  for (int nb = 0; nb < 4; nb++) { accg[nb] = (f32x4)0.f; accu[nb] = (f32x4)0.f; }

  int sr = tid >> 3;            // k-row 0..31
  int sc = (tid & 7) * 8;       // col base 0..56
  const float* WgT = Wg + (size_t)e * H_DIM * I_DIM + n0 + sc;
  const float* WuT = Wu + (size_t)e * H_DIM * I_DIM + n0 + sc;

  for (int k0 = 0; k0 < H_DIM; k0 += 32) {
    const float* pg = WgT + (size_t)(k0 + sr) * I_DIM;
    float4 g0 = *(const float4*)pg, g1 = *(const float4*)(pg + 4);
    const float* pu = WuT + (size_t)(k0 + sr) * I_DIM;
    float4 u0 = *(const float4*)pu, u1 = *(const float4*)(pu + 4);
    __syncthreads();
    Bg[sc + 0][sr] = f2bf(g0.x); Bg[sc + 1][sr] = f2bf(g0.y);
    Bg[sc + 2][sr] = f2bf(g0.z); Bg[sc + 3][sr] = f2bf(g0.w);
    Bg[sc + 4][sr] = f2bf(g1.x); Bg[sc + 5][sr] = f2bf(g1.y);
    Bg[sc + 6][sr] = f2bf(g1.z); Bg[sc + 7][sr] = f2bf(g1.w);
    Bu[sc + 0][sr] = f2bf(u0.x); Bu[sc + 1][sr] = f2bf(u0.y);
    Bu[sc + 2][sr] = f2bf(u0.z); Bu[sc + 3][sr] = f2bf(u0.w);
    Bu[sc + 4][sr] = f2bf(u1.x); Bu[sc + 5][sr] = f2bf(u1.y);
    Bu[sc + 6][sr] = f2bf(u1.z); Bu[sc + 7][sr] = f2bf(u1.w);
    __syncthreads();

    short8 a = *(const short8*)(Arow + k0 + quad * 8);
#pragma unroll
    for (int nb = 0; nb < 4; nb++) {
      short8 bg = *(const short8*)&Bg[nb * 16 + c][quad * 8];
      short8 bu = *(const short8*)&Bu[nb * 16 + c][quad * 8];
      accg[nb] = __builtin_amdgcn_mfma_f32_16x16x32_bf16(a, bg, accg[nb], 0, 0, 0);
      accu[nb] = __builtin_amdgcn_mfma_f32_16x16x32_bf16(a, bu, accu[nb], 0, 0, 0);
    }
  }

#pragma unroll
  for (int nb = 0; nb < 4; nb++) {
#pragma unroll
    for (int r = 0; r < 4; r++) {
      int m = wave * 16 + quad * 4 + r;
      if (m < rows) {
        float g = accg[nb][r], u = accu[nb][r];
        float val = (g / (1.f + __expf(-g))) * u;
        G[(size_t)(mbase + m) * I_DIM + n0 + nb * 16 + c] = f2bf(val);
      }
    }
  }
}

// ---------------- GEMM2: out += p * (G Wd), per expert ----------------
__global__ __launch_bounds__(256) void gemm2_kernel(
    const unsigned short* __restrict__ G, const float* __restrict__ Wd,
    const int* __restrict__ ntiles, const int* __restrict__ tile_e,
    const int* __restrict__ tile_b, const int* __restrict__ tile_r,
    const int* __restrict__ pair_tok, const float* __restrict__ pair_w,
    float* __restrict__ out) {
  int bx = blockIdx.x;
  if (bx >= *ntiles) return;
  int e = tile_e[bx], mbase = tile_b[bx], rows = tile_r[bx];
  int n0 = blockIdx.y * 64;
  int tid = threadIdx.x, wave = tid >> 6, lane = tid & 63;
  int quad = lane >> 4, c = lane & 15;

  __shared__ __align__(16) unsigned short Bd[64][40];

  int mA = wave * 16 + c;
  int rowA = mbase + (mA < rows ? mA : 0);
  const unsigned short* Arow = G + (size_t)rowA * I_DIM;

  f32x4 acc[4];
#pragma unroll
  for (int nb = 0; nb < 4; nb++) acc[nb] = (f32x4)0.f;

  int sr = tid >> 3;
  int sc = (tid & 7) * 8;
  const float* WdT = Wd + (size_t)e * I_DIM * H_DIM + n0 + sc;

  for (int k0 = 0; k0 < I_DIM; k0 += 32) {
    const float* pd = WdT + (size_t)(k0 + sr) * H_DIM;
    float4 d0 = *(const float4*)pd, d1 = *(const float4*)(pd + 4);
    __syncthreads();
    Bd[sc + 0][sr] = f2bf(d0.x); Bd[sc + 1][sr] = f2bf(d0.y);
    Bd[sc + 2][sr] = f2bf(d0.z); Bd[sc + 3][sr] = f2bf(d0.w);
    Bd[sc + 4][sr] = f2bf(d1.x); Bd[sc + 5][sr] = f2bf(d1.y);
    Bd[sc + 6][sr] = f2bf(d1.z); Bd[sc + 7][sr] = f2bf(d1.w);
    __syncthreads();

    short8 a = *(const short8*)(Arow + k0 + quad * 8);
#pragma unroll
    for (int nb = 0; nb < 4; nb++) {
      short8 b = *(const short8*)&Bd[nb * 16 + c][quad * 8];
      acc[nb] = __builtin_amdgcn_mfma_f32_16x16x32_bf16(a, b, acc[nb], 0, 0, 0);
    }
  }

#pragma unroll
  for (int r = 0; r < 4; r++) {
    int m = wave * 16 + quad * 4 + r;
    if (m < rows) {
      int pr = mbase + m;
      int tok = pair_tok[pr];
      float p = pair_w[pr];
      float* orow = out + (size_t)tok * H_DIM + n0 + c;
#pragma unroll
      for (int nb = 0; nb < 4; nb++) atomicAdd(orow + nb * 16, p * acc[nb][r]);
    }
  }
}

extern "C" void kernel_launch(void* const* d_in, const int* in_sizes, int n_in,
                              void* d_out, int out_size, void* d_ws, size_t ws_size,
                              hipStream_t stream) {
  const float* X  = (const float*)d_in[0];
  const float* GW = (const float*)d_in[1];
  const float* Wg = (const float*)d_in[2];
  const float* Wu = (const float*)d_in[3];
  const float* Wd = (const float*)d_in[4];
  float* out = (float*)d_out;

  char* ws = (char*)d_ws;
  int*   counts   = (int*)(ws + 0);
  int*   cursor   = (int*)(ws + 32);
  int*   ntiles   = (int*)(ws + 64);
  int*   tile_e   = (int*)(ws + 128);
  int*   tile_b   = (int*)(ws + 1280);
  int*   tile_r   = (int*)(ws + 2432);
  int*   topk_e   = (int*)(ws + 4096);
  float* topk_p   = (float*)(ws + 69632);
  int*   pair_tok = (int*)(ws + 135168);
  float* pair_w   = (float*)(ws + 200704);
  unsigned short* Xb = (unsigned short*)(ws + 266240);
  unsigned short* G  = (unsigned short*)(ws + 33820672);

  hipMemsetAsync(d_ws, 0, 4096, stream);
  hipMemsetAsync(d_out, 0, (size_t)out_size * sizeof(float), stream);

  router_kernel<<<T_TOK / 4, 256, 0, stream>>>(X, GW, topk_e, topk_p, counts);
  setup_kernel<<<1, 1, 0, stream>>>(counts, cursor, ntiles, tile_e, tile_b, tile_r);
  scatter_kernel<<<T_TOK / 256, 256, 0, stream>>>(topk_e, topk_p, cursor, pair_tok, pair_w);
  cvt_kernel<<<(T_TOK * H_DIM) / 8 / 256, 256, 0, stream>>>(X, Xb);
  gemm1_kernel<<<dim3(MAX_TILES, I_DIM / 64), 256, 0, stream>>>(
      Xb, Wg, Wu, ntiles, tile_e, tile_b, tile_r, pair_tok, G);
  gemm2_kernel<<<dim3(MAX_TILES, H_DIM / 64), 256, 0, stream>>>(
      G, Wd, ntiles, tile_e, tile_b, tile_r, pair_tok, pair_w, out);
}

// Round 2
// 1100.876 us; speedup vs baseline: 1.6287x; 1.6287x over previous
//
#include <hip/hip_runtime.h>

#define T_TOK 8192
#define H_DIM 2048
#define I_DIM 1408
#define N_EXP 8
#define MAX_TILES 144   // 128-row tiles: sum ceil(n_e/128) <= 135

typedef __attribute__((ext_vector_type(8))) short short8;
typedef __attribute__((ext_vector_type(8))) unsigned short ushort8;
typedef __attribute__((ext_vector_type(4))) float f32x4;

// ---- workspace layout (bytes) ----
// 0        counts[8]
// 32       cursor[8]
// 64       ntiles[1]
// 128      tile_e[144]
// 1280     tile_b[144]
// 2432     tile_r[144]
// 4096     topk_e[T*2]
// 69632    topk_p[T*2]
// 135168   pair_tok[16384]
// 200704   pair_w[16384]
// 266240   Xb   bf16 [T][H]        33,554,432
// 33820672 G    bf16 [16384][I]    46,137,344
// 79958016 Wgt  bf16 [E][I][H]     46,137,344   (B^T of w_gate)
// 126095360 Wut bf16 [E][I][H]     46,137,344   (B^T of w_up)
// 172232704 Wdt bf16 [E][H][I]     46,137,344   (B^T of w_down)
// total ~218.4 MB

__device__ __forceinline__ unsigned short f2bf(float f) {
  unsigned u = __float_as_uint(f);
  u += 0x7fffu + ((u >> 16) & 1u);   // RNE
  return (unsigned short)(u >> 16);
}

__device__ __forceinline__ void g2lds16(const unsigned short* g, unsigned short* l) {
  __builtin_amdgcn_global_load_lds(
      (const __attribute__((address_space(1))) void*)g,
      (__attribute__((address_space(3))) void*)l, 16, 0, 0);
}

// ---------------- router: one wave per token ----------------
__global__ __launch_bounds__(256) void router_kernel(
    const float* __restrict__ X, const float* __restrict__ GW,
    int* __restrict__ topk_e, float* __restrict__ topk_p, int* __restrict__ counts) {
  int wave = threadIdx.x >> 6, lane = threadIdx.x & 63;
  int token = blockIdx.x * 4 + wave;
  const float4* x4 = (const float4*)(X + (size_t)token * H_DIM);
  const float4* g4 = (const float4*)GW;
  float acc[8];
#pragma unroll
  for (int e = 0; e < 8; e++) acc[e] = 0.f;
#pragma unroll
  for (int i = 0; i < 8; i++) {
    float4 xv = x4[lane + i * 64];
#pragma unroll
    for (int e = 0; e < 8; e++) {
      float4 gv = g4[e * 512 + lane + i * 64];
      acc[e] += xv.x * gv.x + xv.y * gv.y + xv.z * gv.z + xv.w * gv.w;
    }
  }
#pragma unroll
  for (int e = 0; e < 8; e++)
    for (int off = 32; off; off >>= 1) acc[e] += __shfl_down(acc[e], off);
  if (lane == 0) {
    int e1 = 0; float l1 = acc[0];
#pragma unroll
    for (int e = 1; e < 8; e++) if (acc[e] > l1) { l1 = acc[e]; e1 = e; }
    int e2 = -1; float l2 = -1e30f;
#pragma unroll
    for (int e = 0; e < 8; e++) if (e != e1 && acc[e] > l2) { l2 = acc[e]; e2 = e; }
    float t = __expf(l2 - l1);
    float p1 = 1.f / (1.f + t);
    float p2 = t / (1.f + t);
    topk_e[token * 2] = e1; topk_e[token * 2 + 1] = e2;
    topk_p[token * 2] = p1; topk_p[token * 2 + 1] = p2;
    atomicAdd(&counts[e1], 1);
    atomicAdd(&counts[e2], 1);
  }
}

// ---------------- setup: scan + 128-row tile table ----------------
__global__ void setup_kernel(const int* __restrict__ counts, int* __restrict__ cursor,
                             int* __restrict__ ntiles, int* __restrict__ tile_e,
                             int* __restrict__ tile_b, int* __restrict__ tile_r) {
  int off = 0, nt = 0;
  for (int e = 0; e < N_EXP; e++) {
    cursor[e] = off;
    int n = counts[e];
    for (int t = 0; t * 128 < n; t++) {
      tile_e[nt] = e;
      tile_b[nt] = off + t * 128;
      tile_r[nt] = (n - t * 128) < 128 ? (n - t * 128) : 128;
      nt++;
    }
    off += n;
  }
  *ntiles = nt;
}

// ---------------- scatter pairs ----------------
__global__ void scatter_kernel(const int* __restrict__ topk_e, const float* __restrict__ topk_p,
                               int* __restrict__ cursor, int* __restrict__ pair_tok,
                               float* __restrict__ pair_w) {
  int t = blockIdx.x * 256 + threadIdx.x;
  if (t >= T_TOK) return;
#pragma unroll
  for (int k = 0; k < 2; k++) {
    int e = topk_e[t * 2 + k];
    int pos = atomicAdd(&cursor[e], 1);
    pair_tok[pos] = t;
    pair_w[pos] = topk_p[t * 2 + k];
  }
}

// ---------------- X -> bf16 ----------------
__global__ __launch_bounds__(256) void cvt_kernel(const float* __restrict__ X,
                                                  unsigned short* __restrict__ Xb) {
  int i = blockIdx.x * 256 + threadIdx.x;
  const float4* src = (const float4*)X;
  float4 a = src[2 * i], b = src[2 * i + 1];
  ushort8 v;
  v[0] = f2bf(a.x); v[1] = f2bf(a.y); v[2] = f2bf(a.z); v[3] = f2bf(a.w);
  v[4] = f2bf(b.x); v[5] = f2bf(b.y); v[6] = f2bf(b.z); v[7] = f2bf(b.w);
  *(ushort8*)(Xb + (size_t)i * 8) = v;
}

// ---------------- transpose + convert: in[e][r][c] f32 -> out[e][c][r] bf16 ----------------
__global__ __launch_bounds__(256) void transpose_cvt_kernel(
    const float* __restrict__ in, unsigned short* __restrict__ out, int R, int C) {
  __shared__ float S[64][65];
  int e = blockIdx.z;
  int c0 = blockIdx.x * 64, r0 = blockIdx.y * 64;
  const float* ine = in + (size_t)e * R * C;
  unsigned short* oute = out + (size_t)e * R * C;
  int t = threadIdx.x;
  int li = (t & 15) * 4, lr = t >> 4;
#pragma unroll
  for (int p = 0; p < 4; p++) {
    int r = lr + p * 16;
    float4 v = *(const float4*)(ine + (size_t)(r0 + r) * C + c0 + li);
    S[r][li] = v.x; S[r][li + 1] = v.y; S[r][li + 2] = v.z; S[r][li + 3] = v.w;
  }
  __syncthreads();
#pragma unroll
  for (int p = 0; p < 4; p++) {
    int cc = lr + p * 16;
    ushort4 o;
    o.x = f2bf(S[li][cc]);     o.y = f2bf(S[li + 1][cc]);
    o.z = f2bf(S[li + 2][cc]); o.w = f2bf(S[li + 3][cc]);
    *(ushort4*)(oute + (size_t)(c0 + cc) * R + r0 + li) = o;
  }
}

// ---------------- GEMM1: G = silu(X Wg) * (X Wu) — 128x128x32, m97-style ----------------
__global__ __launch_bounds__(256, 2) void gemm1_kernel(
    const unsigned short* __restrict__ Xb, const unsigned short* __restrict__ Wgt,
    const unsigned short* __restrict__ Wut, const int* __restrict__ ntiles,
    const int* __restrict__ tile_e, const int* __restrict__ tile_b,
    const int* __restrict__ tile_r, const int* __restrict__ pair_tok,
    unsigned short* __restrict__ G) {
  int bx = blockIdx.x;
  if (bx >= *ntiles) return;
  int e = tile_e[bx], mbase = tile_b[bx], rows = tile_r[bx];
  int n0 = blockIdx.y * 128;
  int tid = threadIdx.x, wave = tid >> 6, lane = tid & 63;
  int quad = lane >> 4, c = lane & 15;
  int wm = (wave & 1) * 64, wn = (wave >> 1) * 64;

  __shared__ __align__(16) unsigned short As[128][32];
  __shared__ __align__(16) unsigned short Bgs[128][32];
  __shared__ __align__(16) unsigned short Bus[128][32];

  // staging: wave w covers rows [w*16, w*16+16) (chunk0) and [64+w*16, ...) (chunk1)
  int r0 = wave * 16 + (lane >> 2);
  int r1 = 64 + r0;
  int lofs = (lane & 3) * 8;                 // element offset (16B quarter-row)
  int m0 = mbase + (r0 < rows ? r0 : 0);
  int m1 = mbase + (r1 < rows ? r1 : 0);
  const unsigned short* gA0 = Xb + (size_t)pair_tok[m0] * H_DIM + lofs;
  const unsigned short* gA1 = Xb + (size_t)pair_tok[m1] * H_DIM + lofs;
  const unsigned short* bg = Wgt + (size_t)e * H_DIM * I_DIM;
  const unsigned short* bu = Wut + (size_t)e * H_DIM * I_DIM;
  const unsigned short* gG0 = bg + (size_t)(n0 + r0) * H_DIM + lofs;
  const unsigned short* gG1 = bg + (size_t)(n0 + r1) * H_DIM + lofs;
  const unsigned short* gU0 = bu + (size_t)(n0 + r0) * H_DIM + lofs;
  const unsigned short* gU1 = bu + (size_t)(n0 + r1) * H_DIM + lofs;
  unsigned short* lA0 = &As[wave * 16][0];
  unsigned short* lA1 = &As[64 + wave * 16][0];
  unsigned short* lG0 = &Bgs[wave * 16][0];
  unsigned short* lG1 = &Bgs[64 + wave * 16][0];
  unsigned short* lU0 = &Bus[wave * 16][0];
  unsigned short* lU1 = &Bus[64 + wave * 16][0];

  f32x4 accg[4][4], accu[4][4];
#pragma unroll
  for (int i = 0; i < 4; i++)
#pragma unroll
    for (int j = 0; j < 4; j++) { accg[i][j] = (f32x4)0.f; accu[i][j] = (f32x4)0.f; }

  for (int k0 = 0; k0 < H_DIM; k0 += 32) {
    __syncthreads();
    g2lds16(gA0 + k0, lA0); g2lds16(gA1 + k0, lA1);
    g2lds16(gG0 + k0, lG0); g2lds16(gG1 + k0, lG1);
    g2lds16(gU0 + k0, lU0); g2lds16(gU1 + k0, lU1);
    __syncthreads();

    short8 af[4], bgf[4], buf[4];
#pragma unroll
    for (int mt = 0; mt < 4; mt++)
      af[mt] = *(const short8*)&As[wm + mt * 16 + c][quad * 8];
#pragma unroll
    for (int nt = 0; nt < 4; nt++) {
      bgf[nt] = *(const short8*)&Bgs[wn + nt * 16 + c][quad * 8];
      buf[nt] = *(const short8*)&Bus[wn + nt * 16 + c][quad * 8];
    }
#pragma unroll
    for (int mt = 0; mt < 4; mt++)
#pragma unroll
      for (int nt = 0; nt < 4; nt++) {
        accg[mt][nt] = __builtin_amdgcn_mfma_f32_16x16x32_bf16(af[mt], bgf[nt], accg[mt][nt], 0, 0, 0);
        accu[mt][nt] = __builtin_amdgcn_mfma_f32_16x16x32_bf16(af[mt], buf[nt], accu[mt][nt], 0, 0, 0);
      }
  }

#pragma unroll
  for (int mt = 0; mt < 4; mt++)
#pragma unroll
    for (int r = 0; r < 4; r++) {
      int m = wm + mt * 16 + quad * 4 + r;
      if (m < rows) {
        unsigned short* grow = G + (size_t)(mbase + m) * I_DIM + n0 + wn;
#pragma unroll
        for (int nt = 0; nt < 4; nt++) {
          float g = accg[mt][nt][r], u = accu[mt][nt][r];
          float val = (g / (1.f + __expf(-g))) * u;
          grow[nt * 16 + c] = f2bf(val);
        }
      }
    }
}

// ---------------- GEMM2: out += p * (G Wd) — 128x128x32 ----------------
__global__ __launch_bounds__(256, 2) void gemm2_kernel(
    const unsigned short* __restrict__ G, const unsigned short* __restrict__ Wdt,
    const int* __restrict__ ntiles, const int* __restrict__ tile_e,
    const int* __restrict__ tile_b, const int* __restrict__ tile_r,
    const int* __restrict__ pair_tok, const float* __restrict__ pair_w,
    float* __restrict__ out) {
  int bx = blockIdx.x;
  if (bx >= *ntiles) return;
  int e = tile_e[bx], mbase = tile_b[bx], rows = tile_r[bx];
  int n0 = blockIdx.y * 128;
  int tid = threadIdx.x, wave = tid >> 6, lane = tid & 63;
  int quad = lane >> 4, c = lane & 15;
  int wm = (wave & 1) * 64, wn = (wave >> 1) * 64;

  __shared__ __align__(16) unsigned short As[128][32];
  __shared__ __align__(16) unsigned short Bs[128][32];

  int r0 = wave * 16 + (lane >> 2);
  int r1 = 64 + r0;
  int lofs = (lane & 3) * 8;
  const unsigned short* gA0 = G + (size_t)(mbase + (r0 < rows ? r0 : 0)) * I_DIM + lofs;
  const unsigned short* gA1 = G + (size_t)(mbase + (r1 < rows ? r1 : 0)) * I_DIM + lofs;
  const unsigned short* bd = Wdt + (size_t)e * H_DIM * I_DIM;
  const unsigned short* gB0 = bd + (size_t)(n0 + r0) * I_DIM + lofs;
  const unsigned short* gB1 = bd + (size_t)(n0 + r1) * I_DIM + lofs;
  unsigned short* lA0 = &As[wave * 16][0];
  unsigned short* lA1 = &As[64 + wave * 16][0];
  unsigned short* lB0 = &Bs[wave * 16][0];
  unsigned short* lB1 = &Bs[64 + wave * 16][0];

  f32x4 acc[4][4];
#pragma unroll
  for (int i = 0; i < 4; i++)
#pragma unroll
    for (int j = 0; j < 4; j++) acc[i][j] = (f32x4)0.f;

  for (int k0 = 0; k0 < I_DIM; k0 += 32) {
    __syncthreads();
    g2lds16(gA0 + k0, lA0); g2lds16(gA1 + k0, lA1);
    g2lds16(gB0 + k0, lB0); g2lds16(gB1 + k0, lB1);
    __syncthreads();

    short8 af[4], bf[4];
#pragma unroll
    for (int mt = 0; mt < 4; mt++)
      af[mt] = *(const short8*)&As[wm + mt * 16 + c][quad * 8];
#pragma unroll
    for (int nt = 0; nt < 4; nt++)
      bf[nt] = *(const short8*)&Bs[wn + nt * 16 + c][quad * 8];
#pragma unroll
    for (int mt = 0; mt < 4; mt++)
#pragma unroll
      for (int nt = 0; nt < 4; nt++)
        acc[mt][nt] = __builtin_amdgcn_mfma_f32_16x16x32_bf16(af[mt], bf[nt], acc[mt][nt], 0, 0, 0);
  }

#pragma unroll
  for (int mt = 0; mt < 4; mt++)
#pragma unroll
    for (int r = 0; r < 4; r++) {
      int m = wm + mt * 16 + quad * 4 + r;
      if (m < rows) {
        int pr = mbase + m;
        int tok = pair_tok[pr];
        float p = pair_w[pr];
        float* orow = out + (size_t)tok * H_DIM + n0 + wn;
#pragma unroll
        for (int nt = 0; nt < 4; nt++) atomicAdd(orow + nt * 16 + c, p * acc[mt][nt][r]);
      }
    }
}

extern "C" void kernel_launch(void* const* d_in, const int* in_sizes, int n_in,
                              void* d_out, int out_size, void* d_ws, size_t ws_size,
                              hipStream_t stream) {
  const float* X  = (const float*)d_in[0];
  const float* GW = (const float*)d_in[1];
  const float* Wg = (const float*)d_in[2];
  const float* Wu = (const float*)d_in[3];
  const float* Wd = (const float*)d_in[4];
  float* out = (float*)d_out;

  char* ws = (char*)d_ws;
  int*   counts   = (int*)(ws + 0);
  int*   cursor   = (int*)(ws + 32);
  int*   ntiles   = (int*)(ws + 64);
  int*   tile_e   = (int*)(ws + 128);
  int*   tile_b   = (int*)(ws + 1280);
  int*   tile_r   = (int*)(ws + 2432);
  int*   topk_e   = (int*)(ws + 4096);
  float* topk_p   = (float*)(ws + 69632);
  int*   pair_tok = (int*)(ws + 135168);
  float* pair_w   = (float*)(ws + 200704);
  unsigned short* Xb  = (unsigned short*)(ws + 266240);
  unsigned short* G   = (unsigned short*)(ws + 33820672);
  unsigned short* Wgt = (unsigned short*)(ws + 79958016);
  unsigned short* Wut = (unsigned short*)(ws + 126095360);
  unsigned short* Wdt = (unsigned short*)(ws + 172232704);

  hipMemsetAsync(d_ws, 0, 4096, stream);
  hipMemsetAsync(d_out, 0, (size_t)out_size * sizeof(float), stream);

  router_kernel<<<T_TOK / 4, 256, 0, stream>>>(X, GW, topk_e, topk_p, counts);
  setup_kernel<<<1, 1, 0, stream>>>(counts, cursor, ntiles, tile_e, tile_b, tile_r);
  scatter_kernel<<<T_TOK / 256, 256, 0, stream>>>(topk_e, topk_p, cursor, pair_tok, pair_w);
  cvt_kernel<<<(T_TOK * H_DIM) / 8 / 256, 256, 0, stream>>>(X, Xb);
  // w_gate [E][H][I] -> Wgt [E][I][H]
  transpose_cvt_kernel<<<dim3(I_DIM / 64, H_DIM / 64, N_EXP), 256, 0, stream>>>(Wg, Wgt, H_DIM, I_DIM);
  transpose_cvt_kernel<<<dim3(I_DIM / 64, H_DIM / 64, N_EXP), 256, 0, stream>>>(Wu, Wut, H_DIM, I_DIM);
  // w_down [E][I][H] -> Wdt [E][H][I]
  transpose_cvt_kernel<<<dim3(H_DIM / 64, I_DIM / 64, N_EXP), 256, 0, stream>>>(Wd, Wdt, I_DIM, H_DIM);

  gemm1_kernel<<<dim3(MAX_TILES, I_DIM / 128), 256, 0, stream>>>(
      Xb, Wgt, Wut, ntiles, tile_e, tile_b, tile_r, pair_tok, G);
  gemm2_kernel<<<dim3(MAX_TILES, H_DIM / 128), 256, 0, stream>>>(
      G, Wdt, ntiles, tile_e, tile_b, tile_r, pair_tok, pair_w, out);
}

// Round 3
// 1062.969 us; speedup vs baseline: 1.6868x; 1.0357x over previous
//
#include <hip/hip_runtime.h>

#define T_TOK 8192
#define H_DIM 2048
#define I_DIM 1408
#define N_EXP 8
#define MAX_TILES 144   // 128-row tiles: sum ceil(n_e/128) <= 136

typedef __attribute__((ext_vector_type(8))) short short8;
typedef __attribute__((ext_vector_type(8))) unsigned short ushort8;
typedef __attribute__((ext_vector_type(4))) float f32x4;

// ---- workspace layout (bytes) ----
// 0        counts[8]
// 32       cursor[8]
// 64       ntiles[1]
// 128      tile_e[144]
// 1280     tile_b[144]
// 2432     tile_r[144]
// 4096     topk_e[T*2]
// 69632    topk_p[T*2]
// 135168   pair_tok[16384]
// 200704   pair_w[16384]
// 266240   Xb   bf16 [T][H]        33,554,432
// 33820672 G    bf16 [16384][I]    46,137,344
// 79958016 Wgt  bf16 [E][I][H]     46,137,344
// 126095360 Wut bf16 [E][I][H]     46,137,344
// 172232704 Wdt bf16 [E][H][I]     46,137,344
// total ~218.4 MB

__device__ __forceinline__ unsigned short f2bf(float f) {
  unsigned u = __float_as_uint(f);
  u += 0x7fffu + ((u >> 16) & 1u);   // RNE
  return (unsigned short)(u >> 16);
}

__device__ __forceinline__ void g2lds16(const unsigned short* g, unsigned short* l) {
  __builtin_amdgcn_global_load_lds(
      (const __attribute__((address_space(1))) void*)g,
      (__attribute__((address_space(3))) void*)l, 16, 0, 0);
}

// ---------------- router (+ fused X->bf16 convert): one wave per token ----------------
__global__ __launch_bounds__(256) void router_kernel(
    const float* __restrict__ X, const float* __restrict__ GW,
    int* __restrict__ topk_e, float* __restrict__ topk_p, int* __restrict__ counts,
    unsigned short* __restrict__ Xb) {
  int wave = threadIdx.x >> 6, lane = threadIdx.x & 63;
  int token = blockIdx.x * 4 + wave;
  const float4* x4 = (const float4*)(X + (size_t)token * H_DIM);
  const float4* g4 = (const float4*)GW;
  unsigned short* xb = Xb + (size_t)token * H_DIM;
  float acc[8];
#pragma unroll
  for (int e = 0; e < 8; e++) acc[e] = 0.f;
#pragma unroll
  for (int i = 0; i < 8; i++) {
    float4 xv = x4[lane + i * 64];
    ushort4 o;
    o.x = f2bf(xv.x); o.y = f2bf(xv.y); o.z = f2bf(xv.z); o.w = f2bf(xv.w);
    *(ushort4*)(xb + (size_t)(lane + i * 64) * 4) = o;
#pragma unroll
    for (int e = 0; e < 8; e++) {
      float4 gv = g4[e * 512 + lane + i * 64];
      acc[e] += xv.x * gv.x + xv.y * gv.y + xv.z * gv.z + xv.w * gv.w;
    }
  }
#pragma unroll
  for (int e = 0; e < 8; e++)
    for (int off = 32; off; off >>= 1) acc[e] += __shfl_down(acc[e], off);
  if (lane == 0) {
    int e1 = 0; float l1 = acc[0];
#pragma unroll
    for (int e = 1; e < 8; e++) if (acc[e] > l1) { l1 = acc[e]; e1 = e; }
    int e2 = -1; float l2 = -1e30f;
#pragma unroll
    for (int e = 0; e < 8; e++) if (e != e1 && acc[e] > l2) { l2 = acc[e]; e2 = e; }
    float t = __expf(l2 - l1);
    float p1 = 1.f / (1.f + t);
    float p2 = t / (1.f + t);
    topk_e[token * 2] = e1; topk_e[token * 2 + 1] = e2;
    topk_p[token * 2] = p1; topk_p[token * 2 + 1] = p2;
    atomicAdd(&counts[e1], 1);
    atomicAdd(&counts[e2], 1);
  }
}

// ---------------- setup: scan + 128-row tile table ----------------
__global__ void setup_kernel(const int* __restrict__ counts, int* __restrict__ cursor,
                             int* __restrict__ ntiles, int* __restrict__ tile_e,
                             int* __restrict__ tile_b, int* __restrict__ tile_r) {
  int off = 0, nt = 0;
  for (int e = 0; e < N_EXP; e++) {
    cursor[e] = off;
    int n = counts[e];
    for (int t = 0; t * 128 < n; t++) {
      tile_e[nt] = e;
      tile_b[nt] = off + t * 128;
      tile_r[nt] = (n - t * 128) < 128 ? (n - t * 128) : 128;
      nt++;
    }
    off += n;
  }
  *ntiles = nt;
}

// ---------------- scatter pairs ----------------
__global__ void scatter_kernel(const int* __restrict__ topk_e, const float* __restrict__ topk_p,
                               int* __restrict__ cursor, int* __restrict__ pair_tok,
                               float* __restrict__ pair_w) {
  int t = blockIdx.x * 256 + threadIdx.x;
  if (t >= T_TOK) return;
#pragma unroll
  for (int k = 0; k < 2; k++) {
    int e = topk_e[t * 2 + k];
    int pos = atomicAdd(&cursor[e], 1);
    pair_tok[pos] = t;
    pair_w[pos] = topk_p[t * 2 + k];
  }
}

// ---------------- transpose + convert: in[e][r][c] f32 -> out[e][c][r] bf16 ----------------
__global__ __launch_bounds__(256) void transpose_cvt_kernel(
    const float* __restrict__ in, unsigned short* __restrict__ out, int R, int C) {
  __shared__ float S[64][65];
  int e = blockIdx.z;
  int c0 = blockIdx.x * 64, r0 = blockIdx.y * 64;
  const float* ine = in + (size_t)e * R * C;
  unsigned short* oute = out + (size_t)e * R * C;
  int t = threadIdx.x;
  int li = (t & 15) * 4, lr = t >> 4;
#pragma unroll
  for (int p = 0; p < 4; p++) {
    int r = lr + p * 16;
    float4 v = *(const float4*)(ine + (size_t)(r0 + r) * C + c0 + li);
    S[r][li] = v.x; S[r][li + 1] = v.y; S[r][li + 2] = v.z; S[r][li + 3] = v.w;
  }
  __syncthreads();
  int c = t >> 2, q = t & 3;
#pragma unroll
  for (int i = 0; i < 2; i++) {
    int rb = i * 32 + q * 8;
    ushort8 o;
#pragma unroll
    for (int j = 0; j < 8; j++) o[j] = f2bf(S[rb + j][c]);
    *(ushort8*)(oute + (size_t)(c0 + c) * R + r0 + rb) = o;
  }
}

// ---------------- GEMM1: G = silu(X Wg) * (X Wu) — 128x128, K=64 per barrier ----------------
__global__ __launch_bounds__(256, 2) void gemm1_kernel(
    const unsigned short* __restrict__ Xb, const unsigned short* __restrict__ Wgt,
    const unsigned short* __restrict__ Wut, const int* __restrict__ ntiles,
    const int* __restrict__ tile_e, const int* __restrict__ tile_b,
    const int* __restrict__ tile_r, const int* __restrict__ pair_tok,
    unsigned short* __restrict__ G) {
  int bx = blockIdx.x;
  if (bx >= *ntiles) return;
  int e = tile_e[bx], mbase = tile_b[bx], rows = tile_r[bx];
  int n0 = blockIdx.y * 128;
  int tid = threadIdx.x, wave = tid >> 6, lane = tid & 63;
  int quad = lane >> 4, c = lane & 15;
  int wm = (wave & 1) * 64, wn = (wave >> 1) * 64;

  // two K=32 sub-buffers per operand: one barrier pair per K=64
  __shared__ __align__(16) unsigned short As[2][128][32];
  __shared__ __align__(16) unsigned short Bgs[2][128][32];
  __shared__ __align__(16) unsigned short Bus[2][128][32];

  // staging: wave w covers rows [w*32, w*32+32) of each 128-row sub-buffer,
  // as two 16-row chunks; lane -> (row = +lane/4, elem = (lane&3)*8)
  int srow = wave * 32 + (lane >> 2);
  int selem = (lane & 3) * 8;
  int mr0 = srow < rows ? srow : 0;
  int mr1 = (srow + 16) < rows ? (srow + 16) : 0;
  const unsigned short* gA0 = Xb + (size_t)pair_tok[mbase + mr0] * H_DIM + selem;
  const unsigned short* gA1 = Xb + (size_t)pair_tok[mbase + mr1] * H_DIM + selem;
  const unsigned short* bg = Wgt + (size_t)e * H_DIM * I_DIM;
  const unsigned short* bu = Wut + (size_t)e * H_DIM * I_DIM;
  const unsigned short* gG0 = bg + (size_t)(n0 + srow) * H_DIM + selem;
  const unsigned short* gG1 = bg + (size_t)(n0 + srow + 16) * H_DIM + selem;
  const unsigned short* gU0 = bu + (size_t)(n0 + srow) * H_DIM + selem;
  const unsigned short* gU1 = bu + (size_t)(n0 + srow + 16) * H_DIM + selem;

  f32x4 accg[4][4], accu[4][4];
#pragma unroll
  for (int i = 0; i < 4; i++)
#pragma unroll
    for (int j = 0; j < 4; j++) { accg[i][j] = (f32x4)0.f; accu[i][j] = (f32x4)0.f; }

  for (int k0 = 0; k0 < H_DIM; k0 += 64) {
    __syncthreads();
#pragma unroll
    for (int s = 0; s < 2; s++) {
      int kk = k0 + s * 32;
      g2lds16(gA0 + kk, &As[s][wave * 32][0]);
      g2lds16(gA1 + kk, &As[s][wave * 32 + 16][0]);
      g2lds16(gG0 + kk, &Bgs[s][wave * 32][0]);
      g2lds16(gG1 + kk, &Bgs[s][wave * 32 + 16][0]);
      g2lds16(gU0 + kk, &Bus[s][wave * 32][0]);
      g2lds16(gU1 + kk, &Bus[s][wave * 32 + 16][0]);
    }
    __syncthreads();

#pragma unroll
    for (int h = 0; h < 2; h++) {
      short8 af[4], bgf[4], buf[4];
#pragma unroll
      for (int mt = 0; mt < 4; mt++)
        af[mt] = *(const short8*)&As[h][wm + mt * 16 + c][quad * 8];
#pragma unroll
      for (int nt = 0; nt < 4; nt++) {
        bgf[nt] = *(const short8*)&Bgs[h][wn + nt * 16 + c][quad * 8];
        buf[nt] = *(const short8*)&Bus[h][wn + nt * 16 + c][quad * 8];
      }
#pragma unroll
      for (int mt = 0; mt < 4; mt++)
#pragma unroll
        for (int nt = 0; nt < 4; nt++) {
          accg[mt][nt] = __builtin_amdgcn_mfma_f32_16x16x32_bf16(af[mt], bgf[nt], accg[mt][nt], 0, 0, 0);
          accu[mt][nt] = __builtin_amdgcn_mfma_f32_16x16x32_bf16(af[mt], buf[nt], accu[mt][nt], 0, 0, 0);
        }
    }
  }

#pragma unroll
  for (int mt = 0; mt < 4; mt++)
#pragma unroll
    for (int r = 0; r < 4; r++) {
      int m = wm + mt * 16 + quad * 4 + r;
      if (m < rows) {
        unsigned short* grow = G + (size_t)(mbase + m) * I_DIM + n0 + wn;
#pragma unroll
        for (int nt = 0; nt < 4; nt++) {
          float g = accg[mt][nt][r], u = accu[mt][nt][r];
          float val = (g / (1.f + __expf(-g))) * u;
          grow[nt * 16 + c] = f2bf(val);
        }
      }
    }
}

// ---------------- GEMM2: out += p * (G Wd) — 128x128, K=64 per barrier ----------------
__global__ __launch_bounds__(256, 3) void gemm2_kernel(
    const unsigned short* __restrict__ G, const unsigned short* __restrict__ Wdt,
    const int* __restrict__ ntiles, const int* __restrict__ tile_e,
    const int* __restrict__ tile_b, const int* __restrict__ tile_r,
    const int* __restrict__ pair_tok, const float* __restrict__ pair_w,
    float* __restrict__ out) {
  int bx = blockIdx.x;
  if (bx >= *ntiles) return;
  int e = tile_e[bx], mbase = tile_b[bx], rows = tile_r[bx];
  int n0 = blockIdx.y * 128;
  int tid = threadIdx.x, wave = tid >> 6, lane = tid & 63;
  int quad = lane >> 4, c = lane & 15;
  int wm = (wave & 1) * 64, wn = (wave >> 1) * 64;

  __shared__ __align__(16) unsigned short As[2][128][32];
  __shared__ __align__(16) unsigned short Bs[2][128][32];

  int srow = wave * 32 + (lane >> 2);
  int selem = (lane & 3) * 8;
  int mr0 = srow < rows ? srow : 0;
  int mr1 = (srow + 16) < rows ? (srow + 16) : 0;
  const unsigned short* gA0 = G + (size_t)(mbase + mr0) * I_DIM + selem;
  const unsigned short* gA1 = G + (size_t)(mbase + mr1) * I_DIM + selem;
  const unsigned short* bd = Wdt + (size_t)e * H_DIM * I_DIM;
  const unsigned short* gB0 = bd + (size_t)(n0 + srow) * I_DIM + selem;
  const unsigned short* gB1 = bd + (size_t)(n0 + srow + 16) * I_DIM + selem;

  f32x4 acc[4][4];
#pragma unroll
  for (int i = 0; i < 4; i++)
#pragma unroll
    for (int j = 0; j < 4; j++) acc[i][j] = (f32x4)0.f;

  for (int k0 = 0; k0 < I_DIM; k0 += 64) {
    __syncthreads();
#pragma unroll
    for (int s = 0; s < 2; s++) {
      int kk = k0 + s * 32;
      g2lds16(gA0 + kk, &As[s][wave * 32][0]);
      g2lds16(gA1 + kk, &As[s][wave * 32 + 16][0]);
      g2lds16(gB0 + kk, &Bs[s][wave * 32][0]);
      g2lds16(gB1 + kk, &Bs[s][wave * 32 + 16][0]);
    }
    __syncthreads();

#pragma unroll
    for (int h = 0; h < 2; h++) {
      short8 af[4], bf[4];
#pragma unroll
      for (int mt = 0; mt < 4; mt++)
        af[mt] = *(const short8*)&As[h][wm + mt * 16 + c][quad * 8];
#pragma unroll
      for (int nt = 0; nt < 4; nt++)
        bf[nt] = *(const short8*)&Bs[h][wn + nt * 16 + c][quad * 8];
#pragma unroll
      for (int mt = 0; mt < 4; mt++)
#pragma unroll
        for (int nt = 0; nt < 4; nt++)
          acc[mt][nt] = __builtin_amdgcn_mfma_f32_16x16x32_bf16(af[mt], bf[nt], acc[mt][nt], 0, 0, 0);
    }
  }

#pragma unroll
  for (int mt = 0; mt < 4; mt++)
#pragma unroll
    for (int r = 0; r < 4; r++) {
      int m = wm + mt * 16 + quad * 4 + r;
      if (m < rows) {
        int pr = mbase + m;
        int tok = pair_tok[pr];
        float p = pair_w[pr];
        float* orow = out + (size_t)tok * H_DIM + n0 + wn;
#pragma unroll
        for (int nt = 0; nt < 4; nt++) atomicAdd(orow + nt * 16 + c, p * acc[mt][nt][r]);
      }
    }
}

extern "C" void kernel_launch(void* const* d_in, const int* in_sizes, int n_in,
                              void* d_out, int out_size, void* d_ws, size_t ws_size,
                              hipStream_t stream) {
  const float* X  = (const float*)d_in[0];
  const float* GW = (const float*)d_in[1];
  const float* Wg = (const float*)d_in[2];
  const float* Wu = (const float*)d_in[3];
  const float* Wd = (const float*)d_in[4];
  float* out = (float*)d_out;

  char* ws = (char*)d_ws;
  int*   counts   = (int*)(ws + 0);
  int*   cursor   = (int*)(ws + 32);
  int*   ntiles   = (int*)(ws + 64);
  int*   tile_e   = (int*)(ws + 128);
  int*   tile_b   = (int*)(ws + 1280);
  int*   tile_r   = (int*)(ws + 2432);
  int*   topk_e   = (int*)(ws + 4096);
  float* topk_p   = (float*)(ws + 69632);
  int*   pair_tok = (int*)(ws + 135168);
  float* pair_w   = (float*)(ws + 200704);
  unsigned short* Xb  = (unsigned short*)(ws + 266240);
  unsigned short* G   = (unsigned short*)(ws + 33820672);
  unsigned short* Wgt = (unsigned short*)(ws + 79958016);
  unsigned short* Wut = (unsigned short*)(ws + 126095360);
  unsigned short* Wdt = (unsigned short*)(ws + 172232704);

  hipMemsetAsync(d_ws, 0, 4096, stream);
  hipMemsetAsync(d_out, 0, (size_t)out_size * sizeof(float), stream);

  router_kernel<<<T_TOK / 4, 256, 0, stream>>>(X, GW, topk_e, topk_p, counts, Xb);
  setup_kernel<<<1, 1, 0, stream>>>(counts, cursor, ntiles, tile_e, tile_b, tile_r);
  scatter_kernel<<<T_TOK / 256, 256, 0, stream>>>(topk_e, topk_p, cursor, pair_tok, pair_w);
  // w_gate [E][H][I] -> Wgt [E][I][H]
  transpose_cvt_kernel<<<dim3(I_DIM / 64, H_DIM / 64, N_EXP), 256, 0, stream>>>(Wg, Wgt, H_DIM, I_DIM);
  transpose_cvt_kernel<<<dim3(I_DIM / 64, H_DIM / 64, N_EXP), 256, 0, stream>>>(Wu, Wut, H_DIM, I_DIM);
  // w_down [E][I][H] -> Wdt [E][H][I]
  transpose_cvt_kernel<<<dim3(H_DIM / 64, I_DIM / 64, N_EXP), 256, 0, stream>>>(Wd, Wdt, I_DIM, H_DIM);

  gemm1_kernel<<<dim3(MAX_TILES, I_DIM / 128), 256, 0, stream>>>(
      Xb, Wgt, Wut, ntiles, tile_e, tile_b, tile_r, pair_tok, G);
  gemm2_kernel<<<dim3(MAX_TILES, H_DIM / 128), 256, 0, stream>>>(
      G, Wdt, ntiles, tile_e, tile_b, tile_r, pair_tok, pair_w, out);
}

// Round 4
// 1038.167 us; speedup vs baseline: 1.7271x; 1.0239x over previous
//
#include <hip/hip_runtime.h>

#define T_TOK 8192
#define H_DIM 2048
#define I_DIM 1408
#define N_EXP 8
#define MAX_TILES 144   // 128-row tiles: sum ceil(n_e/128) <= 136

typedef __attribute__((ext_vector_type(8))) short short8;
typedef __attribute__((ext_vector_type(8))) unsigned short ushort8;
typedef __attribute__((ext_vector_type(4))) float f32x4;

// ---- workspace layout (bytes) ----
// 0        counts[8]
// 32       cursor[8]
// 64       ntiles[1]
// 128      tile_e[144]
// 1280     tile_b[144]
// 2432     tile_r[144]
// 4096     topk_e[T*2]
// 69632    topk_p[T*2]
// 135168   pair_tok[16384]
// 200704   slot[16384]          (token,k) -> pair row
// 266240   Xb   bf16 [T][H]        33,554,432
// 33820672 G    bf16 [16384][I]    46,137,344
// 79958016 Wgt  bf16 [E][I][H]     46,137,344   } gemm1 inputs...
// 126095360 Wut bf16 [E][I][H]     46,137,344   } ...then Y bf16 [16384][H] (64MB) overlays 79958016+
// 172232704 Wdt bf16 [E][H][I]     46,137,344
// total ~218.4 MB

__device__ __forceinline__ unsigned short f2bf(float f) {
  unsigned u = __float_as_uint(f);
  u += 0x7fffu + ((u >> 16) & 1u);   // RNE
  return (unsigned short)(u >> 16);
}
__device__ __forceinline__ float bf2f(unsigned short u) {
  return __uint_as_float(((unsigned)u) << 16);
}

__device__ __forceinline__ void g2lds16(const unsigned short* g, unsigned short* l) {
  __builtin_amdgcn_global_load_lds(
      (const __attribute__((address_space(1))) void*)g,
      (__attribute__((address_space(3))) void*)l, 16, 0, 0);
}

// ---------------- router (+ fused X->bf16 convert): one wave per token ----------------
__global__ __launch_bounds__(256) void router_kernel(
    const float* __restrict__ X, const float* __restrict__ GW,
    int* __restrict__ topk_e, float* __restrict__ topk_p, int* __restrict__ counts,
    unsigned short* __restrict__ Xb) {
  int wave = threadIdx.x >> 6, lane = threadIdx.x & 63;
  int token = blockIdx.x * 4 + wave;
  const float4* x4 = (const float4*)(X + (size_t)token * H_DIM);
  const float4* g4 = (const float4*)GW;
  unsigned short* xb = Xb + (size_t)token * H_DIM;
  float acc[8];
#pragma unroll
  for (int e = 0; e < 8; e++) acc[e] = 0.f;
#pragma unroll
  for (int i = 0; i < 8; i++) {
    float4 xv = x4[lane + i * 64];
    ushort4 o;
    o.x = f2bf(xv.x); o.y = f2bf(xv.y); o.z = f2bf(xv.z); o.w = f2bf(xv.w);
    *(ushort4*)(xb + (size_t)(lane + i * 64) * 4) = o;
#pragma unroll
    for (int e = 0; e < 8; e++) {
      float4 gv = g4[e * 512 + lane + i * 64];
      acc[e] += xv.x * gv.x + xv.y * gv.y + xv.z * gv.z + xv.w * gv.w;
    }
  }
#pragma unroll
  for (int e = 0; e < 8; e++)
    for (int off = 32; off; off >>= 1) acc[e] += __shfl_down(acc[e], off);
  if (lane == 0) {
    int e1 = 0; float l1 = acc[0];
#pragma unroll
    for (int e = 1; e < 8; e++) if (acc[e] > l1) { l1 = acc[e]; e1 = e; }
    int e2 = -1; float l2 = -1e30f;
#pragma unroll
    for (int e = 0; e < 8; e++) if (e != e1 && acc[e] > l2) { l2 = acc[e]; e2 = e; }
    float t = __expf(l2 - l1);
    float p1 = 1.f / (1.f + t);
    float p2 = t / (1.f + t);
    topk_e[token * 2] = e1; topk_e[token * 2 + 1] = e2;
    topk_p[token * 2] = p1; topk_p[token * 2 + 1] = p2;
    atomicAdd(&counts[e1], 1);
    atomicAdd(&counts[e2], 1);
  }
}

// ---------------- setup: parallel scan + 128-row tile table (1 block) ----------------
__global__ __launch_bounds__(256) void setup_kernel(
    const int* __restrict__ counts, int* __restrict__ cursor,
    int* __restrict__ ntiles, int* __restrict__ tile_e,
    int* __restrict__ tile_b, int* __restrict__ tile_r) {
  __shared__ int off[9], tb[9], cnt[8];
  int t = threadIdx.x;
  if (t == 0) {
    int o = 0, nt = 0;
    for (int e = 0; e < N_EXP; e++) {
      int n = counts[e];
      cnt[e] = n; off[e] = o; tb[e] = nt;
      cursor[e] = o;
      nt += (n + 127) >> 7;
      o += n;
    }
    off[8] = o; tb[8] = nt;
    *ntiles = nt;
  }
  __syncthreads();
  int total = tb[8];
  for (int i = t; i < total; i += 256) {
    int e = 0;
    while (i >= tb[e + 1]) e++;
    int k = i - tb[e];
    tile_e[i] = e;
    tile_b[i] = off[e] + k * 128;
    int rem = cnt[e] - k * 128;
    tile_r[i] = rem < 128 ? rem : 128;
  }
}

// ---------------- scatter pairs (records slot map for combine) ----------------
__global__ void scatter_kernel(const int* __restrict__ topk_e,
                               int* __restrict__ cursor, int* __restrict__ pair_tok,
                               int* __restrict__ slot) {
  int t = blockIdx.x * 256 + threadIdx.x;
  if (t >= T_TOK) return;
#pragma unroll
  for (int k = 0; k < 2; k++) {
    int e = topk_e[t * 2 + k];
    int pos = atomicAdd(&cursor[e], 1);
    pair_tok[pos] = t;
    slot[t * 2 + k] = pos;
  }
}

// ---------------- transpose + convert: in[e][r][c] f32 -> out[e][c][r] bf16 ----------------
__global__ __launch_bounds__(256) void transpose_cvt_kernel(
    const float* __restrict__ in, unsigned short* __restrict__ out, int R, int C) {
  __shared__ float S[64][65];
  int e = blockIdx.z;
  int c0 = blockIdx.x * 64, r0 = blockIdx.y * 64;
  const float* ine = in + (size_t)e * R * C;
  unsigned short* oute = out + (size_t)e * R * C;
  int t = threadIdx.x;
  int li = (t & 15) * 4, lr = t >> 4;
#pragma unroll
  for (int p = 0; p < 4; p++) {
    int r = lr + p * 16;
    float4 v = *(const float4*)(ine + (size_t)(r0 + r) * C + c0 + li);
    S[r][li] = v.x; S[r][li + 1] = v.y; S[r][li + 2] = v.z; S[r][li + 3] = v.w;
  }
  __syncthreads();
  int c = t >> 2, q = t & 3;
#pragma unroll
  for (int i = 0; i < 2; i++) {
    int rb = i * 32 + q * 8;
    ushort8 o;
#pragma unroll
    for (int j = 0; j < 8; j++) o[j] = f2bf(S[rb + j][c]);
    *(ushort8*)(oute + (size_t)(c0 + c) * R + r0 + rb) = o;
  }
}

// ---------------- GEMM1: G = silu(X Wg) * (X Wu) — 128x128, K=64 per barrier ----------------
__global__ __launch_bounds__(256, 2) void gemm1_kernel(
    const unsigned short* __restrict__ Xb, const unsigned short* __restrict__ Wgt,
    const unsigned short* __restrict__ Wut, const int* __restrict__ ntiles,
    const int* __restrict__ tile_e, const int* __restrict__ tile_b,
    const int* __restrict__ tile_r, const int* __restrict__ pair_tok,
    unsigned short* __restrict__ G) {
  int bx = blockIdx.x;
  if (bx >= *ntiles) return;
  int e = tile_e[bx], mbase = tile_b[bx], rows = tile_r[bx];
  int n0 = blockIdx.y * 128;
  int tid = threadIdx.x, wave = tid >> 6, lane = tid & 63;
  int quad = lane >> 4, c = lane & 15;
  int wm = (wave & 1) * 64, wn = (wave >> 1) * 64;

  __shared__ __align__(16) unsigned short As[2][128][32];
  __shared__ __align__(16) unsigned short Bgs[2][128][32];
  __shared__ __align__(16) unsigned short Bus[2][128][32];

  int srow = wave * 32 + (lane >> 2);
  int selem = (lane & 3) * 8;
  int mr0 = srow < rows ? srow : 0;
  int mr1 = (srow + 16) < rows ? (srow + 16) : 0;
  const unsigned short* gA0 = Xb + (size_t)pair_tok[mbase + mr0] * H_DIM + selem;
  const unsigned short* gA1 = Xb + (size_t)pair_tok[mbase + mr1] * H_DIM + selem;
  const unsigned short* bg = Wgt + (size_t)e * H_DIM * I_DIM;
  const unsigned short* bu = Wut + (size_t)e * H_DIM * I_DIM;
  const unsigned short* gG0 = bg + (size_t)(n0 + srow) * H_DIM + selem;
  const unsigned short* gG1 = bg + (size_t)(n0 + srow + 16) * H_DIM + selem;
  const unsigned short* gU0 = bu + (size_t)(n0 + srow) * H_DIM + selem;
  const unsigned short* gU1 = bu + (size_t)(n0 + srow + 16) * H_DIM + selem;

  f32x4 accg[4][4], accu[4][4];
#pragma unroll
  for (int i = 0; i < 4; i++)
#pragma unroll
    for (int j = 0; j < 4; j++) { accg[i][j] = (f32x4)0.f; accu[i][j] = (f32x4)0.f; }

  for (int k0 = 0; k0 < H_DIM; k0 += 64) {
    __syncthreads();
#pragma unroll
    for (int s = 0; s < 2; s++) {
      int kk = k0 + s * 32;
      g2lds16(gA0 + kk, &As[s][wave * 32][0]);
      g2lds16(gA1 + kk, &As[s][wave * 32 + 16][0]);
      g2lds16(gG0 + kk, &Bgs[s][wave * 32][0]);
      g2lds16(gG1 + kk, &Bgs[s][wave * 32 + 16][0]);
      g2lds16(gU0 + kk, &Bus[s][wave * 32][0]);
      g2lds16(gU1 + kk, &Bus[s][wave * 32 + 16][0]);
    }
    __syncthreads();

#pragma unroll
    for (int h = 0; h < 2; h++) {
      short8 af[4], bgf[4], buf[4];
#pragma unroll
      for (int mt = 0; mt < 4; mt++)
        af[mt] = *(const short8*)&As[h][wm + mt * 16 + c][quad * 8];
#pragma unroll
      for (int nt = 0; nt < 4; nt++) {
        bgf[nt] = *(const short8*)&Bgs[h][wn + nt * 16 + c][quad * 8];
        buf[nt] = *(const short8*)&Bus[h][wn + nt * 16 + c][quad * 8];
      }
#pragma unroll
      for (int mt = 0; mt < 4; mt++)
#pragma unroll
        for (int nt = 0; nt < 4; nt++) {
          accg[mt][nt] = __builtin_amdgcn_mfma_f32_16x16x32_bf16(af[mt], bgf[nt], accg[mt][nt], 0, 0, 0);
          accu[mt][nt] = __builtin_amdgcn_mfma_f32_16x16x32_bf16(af[mt], buf[nt], accu[mt][nt], 0, 0, 0);
        }
    }
  }

#pragma unroll
  for (int mt = 0; mt < 4; mt++)
#pragma unroll
    for (int r = 0; r < 4; r++) {
      int m = wm + mt * 16 + quad * 4 + r;
      if (m < rows) {
        unsigned short* grow = G + (size_t)(mbase + m) * I_DIM + n0 + wn;
#pragma unroll
        for (int nt = 0; nt < 4; nt++) {
          float g = accg[mt][nt][r], u = accu[mt][nt][r];
          float val = (g / (1.f + __expf(-g))) * u;
          grow[nt * 16 + c] = f2bf(val);
        }
      }
    }
}

// ---------------- GEMM2: Y[pair] = G[pair] @ Wd_e — plain bf16 stores ----------------
__global__ __launch_bounds__(256, 2) void gemm2_kernel(
    const unsigned short* __restrict__ G, const unsigned short* __restrict__ Wdt,
    const int* __restrict__ ntiles, const int* __restrict__ tile_e,
    const int* __restrict__ tile_b, const int* __restrict__ tile_r,
    unsigned short* __restrict__ Y) {
  int bx = blockIdx.x;
  if (bx >= *ntiles) return;
  int e = tile_e[bx], mbase = tile_b[bx], rows = tile_r[bx];
  int n0 = blockIdx.y * 128;
  int tid = threadIdx.x, wave = tid >> 6, lane = tid & 63;
  int quad = lane >> 4, c = lane & 15;
  int wm = (wave & 1) * 64, wn = (wave >> 1) * 64;

  __shared__ __align__(16) unsigned short As[2][128][32];
  __shared__ __align__(16) unsigned short Bs[2][128][32];

  int srow = wave * 32 + (lane >> 2);
  int selem = (lane & 3) * 8;
  int mr0 = srow < rows ? srow : 0;
  int mr1 = (srow + 16) < rows ? (srow + 16) : 0;
  const unsigned short* gA0 = G + (size_t)(mbase + mr0) * I_DIM + selem;
  const unsigned short* gA1 = G + (size_t)(mbase + mr1) * I_DIM + selem;
  const unsigned short* bd = Wdt + (size_t)e * H_DIM * I_DIM;
  const unsigned short* gB0 = bd + (size_t)(n0 + srow) * I_DIM + selem;
  const unsigned short* gB1 = bd + (size_t)(n0 + srow + 16) * I_DIM + selem;

  f32x4 acc[4][4];
#pragma unroll
  for (int i = 0; i < 4; i++)
#pragma unroll
    for (int j = 0; j < 4; j++) acc[i][j] = (f32x4)0.f;

  for (int k0 = 0; k0 < I_DIM; k0 += 64) {
    __syncthreads();
#pragma unroll
    for (int s = 0; s < 2; s++) {
      int kk = k0 + s * 32;
      g2lds16(gA0 + kk, &As[s][wave * 32][0]);
      g2lds16(gA1 + kk, &As[s][wave * 32 + 16][0]);
      g2lds16(gB0 + kk, &Bs[s][wave * 32][0]);
      g2lds16(gB1 + kk, &Bs[s][wave * 32 + 16][0]);
    }
    __syncthreads();

#pragma unroll
    for (int h = 0; h < 2; h++) {
      short8 af[4], bf[4];
#pragma unroll
      for (int mt = 0; mt < 4; mt++)
        af[mt] = *(const short8*)&As[h][wm + mt * 16 + c][quad * 8];
#pragma unroll
      for (int nt = 0; nt < 4; nt++)
        bf[nt] = *(const short8*)&Bs[h][wn + nt * 16 + c][quad * 8];
#pragma unroll
      for (int mt = 0; mt < 4; mt++)
#pragma unroll
        for (int nt = 0; nt < 4; nt++)
          acc[mt][nt] = __builtin_amdgcn_mfma_f32_16x16x32_bf16(af[mt], bf[nt], acc[mt][nt], 0, 0, 0);
    }
  }

#pragma unroll
  for (int mt = 0; mt < 4; mt++)
#pragma unroll
    for (int r = 0; r < 4; r++) {
      int m = wm + mt * 16 + quad * 4 + r;
      if (m < rows) {
        unsigned short* yrow = Y + (size_t)(mbase + m) * H_DIM + n0 + wn;
#pragma unroll
        for (int nt = 0; nt < 4; nt++) yrow[nt * 16 + c] = f2bf(acc[mt][nt][r]);
      }
    }
}

// ---------------- combine: out[t] = p1*Y[s1] + p2*Y[s2] ----------------
__global__ __launch_bounds__(256) void combine_kernel(
    const unsigned short* __restrict__ Y, const int* __restrict__ slot,
    const float* __restrict__ topk_p, float* __restrict__ out) {
  int t = blockIdx.x;
  int h = threadIdx.x * 8;
  int s1 = slot[t * 2], s2 = slot[t * 2 + 1];
  float p1 = topk_p[t * 2], p2 = topk_p[t * 2 + 1];
  ushort8 a = *(const ushort8*)(Y + (size_t)s1 * H_DIM + h);
  ushort8 b = *(const ushort8*)(Y + (size_t)s2 * H_DIM + h);
  float* o = out + (size_t)t * H_DIM + h;
  float4 o0, o1;
  o0.x = p1 * bf2f(a[0]) + p2 * bf2f(b[0]);
  o0.y = p1 * bf2f(a[1]) + p2 * bf2f(b[1]);
  o0.z = p1 * bf2f(a[2]) + p2 * bf2f(b[2]);
  o0.w = p1 * bf2f(a[3]) + p2 * bf2f(b[3]);
  o1.x = p1 * bf2f(a[4]) + p2 * bf2f(b[4]);
  o1.y = p1 * bf2f(a[5]) + p2 * bf2f(b[5]);
  o1.z = p1 * bf2f(a[6]) + p2 * bf2f(b[6]);
  o1.w = p1 * bf2f(a[7]) + p2 * bf2f(b[7]);
  *(float4*)o = o0;
  *(float4*)(o + 4) = o1;
}

extern "C" void kernel_launch(void* const* d_in, const int* in_sizes, int n_in,
                              void* d_out, int out_size, void* d_ws, size_t ws_size,
                              hipStream_t stream) {
  const float* X  = (const float*)d_in[0];
  const float* GW = (const float*)d_in[1];
  const float* Wg = (const float*)d_in[2];
  const float* Wu = (const float*)d_in[3];
  const float* Wd = (const float*)d_in[4];
  float* out = (float*)d_out;

  char* ws = (char*)d_ws;
  int*   counts   = (int*)(ws + 0);
  int*   cursor   = (int*)(ws + 32);
  int*   ntiles   = (int*)(ws + 64);
  int*   tile_e   = (int*)(ws + 128);
  int*   tile_b   = (int*)(ws + 1280);
  int*   tile_r   = (int*)(ws + 2432);
  int*   topk_e   = (int*)(ws + 4096);
  float* topk_p   = (float*)(ws + 69632);
  int*   pair_tok = (int*)(ws + 135168);
  int*   slot     = (int*)(ws + 200704);
  unsigned short* Xb  = (unsigned short*)(ws + 266240);
  unsigned short* G   = (unsigned short*)(ws + 33820672);
  unsigned short* Wgt = (unsigned short*)(ws + 79958016);
  unsigned short* Wut = (unsigned short*)(ws + 126095360);
  unsigned short* Wdt = (unsigned short*)(ws + 172232704);
  unsigned short* Y   = (unsigned short*)(ws + 79958016);  // overlays Wgt/Wut (dead after gemm1)

  hipMemsetAsync(d_ws, 0, 4096, stream);

  router_kernel<<<T_TOK / 4, 256, 0, stream>>>(X, GW, topk_e, topk_p, counts, Xb);
  setup_kernel<<<1, 256, 0, stream>>>(counts, cursor, ntiles, tile_e, tile_b, tile_r);
  scatter_kernel<<<T_TOK / 256, 256, 0, stream>>>(topk_e, cursor, pair_tok, slot);
  // w_gate [E][H][I] -> Wgt [E][I][H]
  transpose_cvt_kernel<<<dim3(I_DIM / 64, H_DIM / 64, N_EXP), 256, 0, stream>>>(Wg, Wgt, H_DIM, I_DIM);
  transpose_cvt_kernel<<<dim3(I_DIM / 64, H_DIM / 64, N_EXP), 256, 0, stream>>>(Wu, Wut, H_DIM, I_DIM);
  // w_down [E][I][H] -> Wdt [E][H][I]
  transpose_cvt_kernel<<<dim3(H_DIM / 64, I_DIM / 64, N_EXP), 256, 0, stream>>>(Wd, Wdt, I_DIM, H_DIM);

  gemm1_kernel<<<dim3(MAX_TILES, I_DIM / 128), 256, 0, stream>>>(
      Xb, Wgt, Wut, ntiles, tile_e, tile_b, tile_r, pair_tok, G);
  gemm2_kernel<<<dim3(MAX_TILES, H_DIM / 128), 256, 0, stream>>>(
      G, Wdt, ntiles, tile_e, tile_b, tile_r, Y);
  combine_kernel<<<T_TOK, 256, 0, stream>>>(Y, slot, topk_p, out);
}

// Round 5
// 1034.357 us; speedup vs baseline: 1.7334x; 1.0037x over previous
//
#include <hip/hip_runtime.h>

#define T_TOK 8192
#define H_DIM 2048
#define I_DIM 1408
#define N_EXP 8
#define MAX_TILES 144   // 128-row tiles: sum ceil(n_e/128) <= 136

typedef __attribute__((ext_vector_type(8))) short short8;
typedef __attribute__((ext_vector_type(8))) unsigned short ushort8;
typedef __attribute__((ext_vector_type(4))) float f32x4;

// ---- workspace layout (bytes) ----
// 0        counts[8]
// 32       cursor[8]
// 64       ntiles[1]
// 128      tile_e[144]
// 1280     tile_b[144]
// 2432     tile_r[144]
// 4096     topk_e[T*2]
// 69632    topk_p[T*2]
// 135168   pair_tok[16384]
// 200704   slot[16384]
// 266240   Xb   bf16 [T][H]        33,554,432
// 33820672 G    bf16 [16384][I]    46,137,344
// 79958016 Wgt  bf16 [E][I][H]     46,137,344   } gemm1 inputs, then Y bf16 [16384][H] overlays
// 126095360 Wut bf16 [E][I][H]     46,137,344
// 172232704 Wdt bf16 [E][H][I]     46,137,344

__device__ __forceinline__ unsigned short f2bf(float f) {
  unsigned u = __float_as_uint(f);
  u += 0x7fffu + ((u >> 16) & 1u);   // RNE
  return (unsigned short)(u >> 16);
}
__device__ __forceinline__ float bf2f(unsigned short u) {
  return __uint_as_float(((unsigned)u) << 16);
}

__device__ __forceinline__ void g2lds16(const unsigned short* g, unsigned short* l) {
  __builtin_amdgcn_global_load_lds(
      (const __attribute__((address_space(1))) void*)g,
      (__attribute__((address_space(3))) void*)l, 16, 0, 0);
}

// ---------------- router (+ fused X->bf16 convert): one wave per token ----------------
__global__ __launch_bounds__(256) void router_kernel(
    const float* __restrict__ X, const float* __restrict__ GW,
    int* __restrict__ topk_e, float* __restrict__ topk_p, int* __restrict__ counts,
    unsigned short* __restrict__ Xb) {
  int wave = threadIdx.x >> 6, lane = threadIdx.x & 63;
  int token = blockIdx.x * 4 + wave;
  const float4* x4 = (const float4*)(X + (size_t)token * H_DIM);
  const float4* g4 = (const float4*)GW;
  unsigned short* xb = Xb + (size_t)token * H_DIM;
  float acc[8];
#pragma unroll
  for (int e = 0; e < 8; e++) acc[e] = 0.f;
#pragma unroll
  for (int i = 0; i < 8; i++) {
    float4 xv = x4[lane + i * 64];
    ushort4 o;
    o.x = f2bf(xv.x); o.y = f2bf(xv.y); o.z = f2bf(xv.z); o.w = f2bf(xv.w);
    *(ushort4*)(xb + (size_t)(lane + i * 64) * 4) = o;
#pragma unroll
    for (int e = 0; e < 8; e++) {
      float4 gv = g4[e * 512 + lane + i * 64];
      acc[e] += xv.x * gv.x + xv.y * gv.y + xv.z * gv.z + xv.w * gv.w;
    }
  }
#pragma unroll
  for (int e = 0; e < 8; e++)
    for (int off = 32; off; off >>= 1) acc[e] += __shfl_down(acc[e], off);
  if (lane == 0) {
    int e1 = 0; float l1 = acc[0];
#pragma unroll
    for (int e = 1; e < 8; e++) if (acc[e] > l1) { l1 = acc[e]; e1 = e; }
    int e2 = -1; float l2 = -1e30f;
#pragma unroll
    for (int e = 0; e < 8; e++) if (e != e1 && acc[e] > l2) { l2 = acc[e]; e2 = e; }
    float t = __expf(l2 - l1);
    float p1 = 1.f / (1.f + t);
    float p2 = t / (1.f + t);
    topk_e[token * 2] = e1; topk_e[token * 2 + 1] = e2;
    topk_p[token * 2] = p1; topk_p[token * 2 + 1] = p2;
    atomicAdd(&counts[e1], 1);
    atomicAdd(&counts[e2], 1);
  }
}

// ---------------- setup: parallel scan + 128-row tile table (1 block) ----------------
__global__ __launch_bounds__(256) void setup_kernel(
    const int* __restrict__ counts, int* __restrict__ cursor,
    int* __restrict__ ntiles, int* __restrict__ tile_e,
    int* __restrict__ tile_b, int* __restrict__ tile_r) {
  __shared__ int off[9], tb[9], cnt[8];
  int t = threadIdx.x;
  if (t == 0) {
    int o = 0, nt = 0;
    for (int e = 0; e < N_EXP; e++) {
      int n = counts[e];
      cnt[e] = n; off[e] = o; tb[e] = nt;
      cursor[e] = o;
      nt += (n + 127) >> 7;
      o += n;
    }
    off[8] = o; tb[8] = nt;
    *ntiles = nt;
  }
  __syncthreads();
  int total = tb[8];
  for (int i = t; i < total; i += 256) {
    int e = 0;
    while (i >= tb[e + 1]) e++;
    int k = i - tb[e];
    tile_e[i] = e;
    tile_b[i] = off[e] + k * 128;
    int rem = cnt[e] - k * 128;
    tile_r[i] = rem < 128 ? rem : 128;
  }
}

// ---------------- scatter pairs (records slot map for combine) ----------------
__global__ void scatter_kernel(const int* __restrict__ topk_e,
                               int* __restrict__ cursor, int* __restrict__ pair_tok,
                               int* __restrict__ slot) {
  int t = blockIdx.x * 256 + threadIdx.x;
  if (t >= T_TOK) return;
#pragma unroll
  for (int k = 0; k < 2; k++) {
    int e = topk_e[t * 2 + k];
    int pos = atomicAdd(&cursor[e], 1);
    pair_tok[pos] = t;
    slot[t * 2 + k] = pos;
  }
}

// ---------------- transpose + convert: in[e][r][c] f32 -> out[e][c][r] bf16 ----------------
__global__ __launch_bounds__(256) void transpose_cvt_kernel(
    const float* __restrict__ in, unsigned short* __restrict__ out, int R, int C) {
  __shared__ float S[64][65];
  int e = blockIdx.z;
  int c0 = blockIdx.x * 64, r0 = blockIdx.y * 64;
  const float* ine = in + (size_t)e * R * C;
  unsigned short* oute = out + (size_t)e * R * C;
  int t = threadIdx.x;
  int li = (t & 15) * 4, lr = t >> 4;
#pragma unroll
  for (int p = 0; p < 4; p++) {
    int r = lr + p * 16;
    float4 v = *(const float4*)(ine + (size_t)(r0 + r) * C + c0 + li);
    S[r][li] = v.x; S[r][li + 1] = v.y; S[r][li + 2] = v.z; S[r][li + 3] = v.w;
  }
  __syncthreads();
  int c = t >> 2, q = t & 3;
#pragma unroll
  for (int i = 0; i < 2; i++) {
    int rb = i * 32 + q * 8;
    ushort8 o;
#pragma unroll
    for (int j = 0; j < 8; j++) o[j] = f2bf(S[rb + j][c]);
    *(ushort8*)(oute + (size_t)(c0 + c) * R + r0 + rb) = o;
  }
}

// ---------------- GEMM1: G = silu(X Wg) * (X Wu) — 128x128, K=64 per barrier ----------------
// grid: (n_blocks=11, tiles) — n fastest so concurrent blocks share A rows (L2/L3 reuse)
__global__ __launch_bounds__(256, 2) void gemm1_kernel(
    const unsigned short* __restrict__ Xb, const unsigned short* __restrict__ Wgt,
    const unsigned short* __restrict__ Wut, const int* __restrict__ ntiles,
    const int* __restrict__ tile_e, const int* __restrict__ tile_b,
    const int* __restrict__ tile_r, const int* __restrict__ pair_tok,
    unsigned short* __restrict__ G, int tile_base) {
  int bx = blockIdx.y + tile_base;
  if (bx >= *ntiles) return;
  int e = tile_e[bx], mbase = tile_b[bx], rows = tile_r[bx];
  int n0 = blockIdx.x * 128;
  int tid = threadIdx.x, wave = tid >> 6, lane = tid & 63;
  int quad = lane >> 4, c = lane & 15;
  int wm = (wave & 1) * 64, wn = (wave >> 1) * 64;

  __shared__ __align__(16) unsigned short As[2][128][32];
  __shared__ __align__(16) unsigned short Bgs[2][128][32];
  __shared__ __align__(16) unsigned short Bus[2][128][32];

  int srow = wave * 32 + (lane >> 2);
  int selem = (lane & 3) * 8;
  int mr0 = srow < rows ? srow : 0;
  int mr1 = (srow + 16) < rows ? (srow + 16) : 0;
  const unsigned short* gA0 = Xb + (size_t)pair_tok[mbase + mr0] * H_DIM + selem;
  const unsigned short* gA1 = Xb + (size_t)pair_tok[mbase + mr1] * H_DIM + selem;
  const unsigned short* bg = Wgt + (size_t)e * H_DIM * I_DIM;
  const unsigned short* bu = Wut + (size_t)e * H_DIM * I_DIM;
  const unsigned short* gG0 = bg + (size_t)(n0 + srow) * H_DIM + selem;
  const unsigned short* gG1 = bg + (size_t)(n0 + srow + 16) * H_DIM + selem;
  const unsigned short* gU0 = bu + (size_t)(n0 + srow) * H_DIM + selem;
  const unsigned short* gU1 = bu + (size_t)(n0 + srow + 16) * H_DIM + selem;

  f32x4 accg[4][4], accu[4][4];
#pragma unroll
  for (int i = 0; i < 4; i++)
#pragma unroll
    for (int j = 0; j < 4; j++) { accg[i][j] = (f32x4)0.f; accu[i][j] = (f32x4)0.f; }

  for (int k0 = 0; k0 < H_DIM; k0 += 64) {
    __syncthreads();
#pragma unroll
    for (int s = 0; s < 2; s++) {
      int kk = k0 + s * 32;
      g2lds16(gA0 + kk, &As[s][wave * 32][0]);
      g2lds16(gA1 + kk, &As[s][wave * 32 + 16][0]);
      g2lds16(gG0 + kk, &Bgs[s][wave * 32][0]);
      g2lds16(gG1 + kk, &Bgs[s][wave * 32 + 16][0]);
      g2lds16(gU0 + kk, &Bus[s][wave * 32][0]);
      g2lds16(gU1 + kk, &Bus[s][wave * 32 + 16][0]);
    }
    __syncthreads();

#pragma unroll
    for (int h = 0; h < 2; h++) {
      short8 af[4], bgf[4], buf[4];
#pragma unroll
      for (int mt = 0; mt < 4; mt++)
        af[mt] = *(const short8*)&As[h][wm + mt * 16 + c][quad * 8];
#pragma unroll
      for (int nt = 0; nt < 4; nt++) {
        bgf[nt] = *(const short8*)&Bgs[h][wn + nt * 16 + c][quad * 8];
        buf[nt] = *(const short8*)&Bus[h][wn + nt * 16 + c][quad * 8];
      }
#pragma unroll
      for (int mt = 0; mt < 4; mt++)
#pragma unroll
        for (int nt = 0; nt < 4; nt++) {
          accg[mt][nt] = __builtin_amdgcn_mfma_f32_16x16x32_bf16(af[mt], bgf[nt], accg[mt][nt], 0, 0, 0);
          accu[mt][nt] = __builtin_amdgcn_mfma_f32_16x16x32_bf16(af[mt], buf[nt], accu[mt][nt], 0, 0, 0);
        }
    }
  }

#pragma unroll
  for (int mt = 0; mt < 4; mt++)
#pragma unroll
    for (int r = 0; r < 4; r++) {
      int m = wm + mt * 16 + quad * 4 + r;
      if (m < rows) {
        unsigned short* grow = G + (size_t)(mbase + m) * I_DIM + n0 + wn;
#pragma unroll
        for (int nt = 0; nt < 4; nt++) {
          float g = accg[mt][nt][r], u = accu[mt][nt][r];
          float val = (g / (1.f + __expf(-g))) * u;
          grow[nt * 16 + c] = f2bf(val);
        }
      }
    }
}

// ---------------- GEMM2: Y[pair] = G[pair] @ Wd_e — grid (n=16, tiles) ----------------
__global__ __launch_bounds__(256, 3) void gemm2_kernel(
    const unsigned short* __restrict__ G, const unsigned short* __restrict__ Wdt,
    const int* __restrict__ ntiles, const int* __restrict__ tile_e,
    const int* __restrict__ tile_b, const int* __restrict__ tile_r,
    unsigned short* __restrict__ Y) {
  int bx = blockIdx.y;
  if (bx >= *ntiles) return;
  int e = tile_e[bx], mbase = tile_b[bx], rows = tile_r[bx];
  int n0 = blockIdx.x * 128;
  int tid = threadIdx.x, wave = tid >> 6, lane = tid & 63;
  int quad = lane >> 4, c = lane & 15;
  int wm = (wave & 1) * 64, wn = (wave >> 1) * 64;

  __shared__ __align__(16) unsigned short As[2][128][32];
  __shared__ __align__(16) unsigned short Bs[2][128][32];

  int srow = wave * 32 + (lane >> 2);
  int selem = (lane & 3) * 8;
  int mr0 = srow < rows ? srow : 0;
  int mr1 = (srow + 16) < rows ? (srow + 16) : 0;
  const unsigned short* gA0 = G + (size_t)(mbase + mr0) * I_DIM + selem;
  const unsigned short* gA1 = G + (size_t)(mbase + mr1) * I_DIM + selem;
  const unsigned short* bd = Wdt + (size_t)e * H_DIM * I_DIM;
  const unsigned short* gB0 = bd + (size_t)(n0 + srow) * I_DIM + selem;
  const unsigned short* gB1 = bd + (size_t)(n0 + srow + 16) * I_DIM + selem;

  f32x4 acc[4][4];
#pragma unroll
  for (int i = 0; i < 4; i++)
#pragma unroll
    for (int j = 0; j < 4; j++) acc[i][j] = (f32x4)0.f;

  for (int k0 = 0; k0 < I_DIM; k0 += 64) {
    __syncthreads();
#pragma unroll
    for (int s = 0; s < 2; s++) {
      int kk = k0 + s * 32;
      g2lds16(gA0 + kk, &As[s][wave * 32][0]);
      g2lds16(gA1 + kk, &As[s][wave * 32 + 16][0]);
      g2lds16(gB0 + kk, &Bs[s][wave * 32][0]);
      g2lds16(gB1 + kk, &Bs[s][wave * 32 + 16][0]);
    }
    __syncthreads();

#pragma unroll
    for (int h = 0; h < 2; h++) {
      short8 af[4], bf[4];
#pragma unroll
      for (int mt = 0; mt < 4; mt++)
        af[mt] = *(const short8*)&As[h][wm + mt * 16 + c][quad * 8];
#pragma unroll
      for (int nt = 0; nt < 4; nt++)
        bf[nt] = *(const short8*)&Bs[h][wn + nt * 16 + c][quad * 8];
#pragma unroll
      for (int mt = 0; mt < 4; mt++)
#pragma unroll
        for (int nt = 0; nt < 4; nt++)
          acc[mt][nt] = __builtin_amdgcn_mfma_f32_16x16x32_bf16(af[mt], bf[nt], acc[mt][nt], 0, 0, 0);
    }
  }

#pragma unroll
  for (int mt = 0; mt < 4; mt++)
#pragma unroll
    for (int r = 0; r < 4; r++) {
      int m = wm + mt * 16 + quad * 4 + r;
      if (m < rows) {
        unsigned short* yrow = Y + (size_t)(mbase + m) * H_DIM + n0 + wn;
#pragma unroll
        for (int nt = 0; nt < 4; nt++) yrow[nt * 16 + c] = f2bf(acc[mt][nt][r]);
      }
    }
}

// ---------------- combine: out[t] = p1*Y[s1] + p2*Y[s2] ----------------
__global__ __launch_bounds__(256) void combine_kernel(
    const unsigned short* __restrict__ Y, const int* __restrict__ slot,
    const float* __restrict__ topk_p, float* __restrict__ out) {
  int t = blockIdx.x;
  int h = threadIdx.x * 8;
  int s1 = slot[t * 2], s2 = slot[t * 2 + 1];
  float p1 = topk_p[t * 2], p2 = topk_p[t * 2 + 1];
  ushort8 a = *(const ushort8*)(Y + (size_t)s1 * H_DIM + h);
  ushort8 b = *(const ushort8*)(Y + (size_t)s2 * H_DIM + h);
  float* o = out + (size_t)t * H_DIM + h;
  float4 o0, o1;
  o0.x = p1 * bf2f(a[0]) + p2 * bf2f(b[0]);
  o0.y = p1 * bf2f(a[1]) + p2 * bf2f(b[1]);
  o0.z = p1 * bf2f(a[2]) + p2 * bf2f(b[2]);
  o0.w = p1 * bf2f(a[3]) + p2 * bf2f(b[3]);
  o1.x = p1 * bf2f(a[4]) + p2 * bf2f(b[4]);
  o1.y = p1 * bf2f(a[5]) + p2 * bf2f(b[5]);
  o1.z = p1 * bf2f(a[6]) + p2 * bf2f(b[6]);
  o1.w = p1 * bf2f(a[7]) + p2 * bf2f(b[7]);
  *(float4*)o = o0;
  *(float4*)(o + 4) = o1;
}

extern "C" void kernel_launch(void* const* d_in, const int* in_sizes, int n_in,
                              void* d_out, int out_size, void* d_ws, size_t ws_size,
                              hipStream_t stream) {
  const float* X  = (const float*)d_in[0];
  const float* GW = (const float*)d_in[1];
  const float* Wg = (const float*)d_in[2];
  const float* Wu = (const float*)d_in[3];
  const float* Wd = (const float*)d_in[4];
  float* out = (float*)d_out;

  char* ws = (char*)d_ws;
  int*   counts   = (int*)(ws + 0);
  int*   cursor   = (int*)(ws + 32);
  int*   ntiles   = (int*)(ws + 64);
  int*   tile_e   = (int*)(ws + 128);
  int*   tile_b   = (int*)(ws + 1280);
  int*   tile_r   = (int*)(ws + 2432);
  int*   topk_e   = (int*)(ws + 4096);
  float* topk_p   = (float*)(ws + 69632);
  int*   pair_tok = (int*)(ws + 135168);
  int*   slot     = (int*)(ws + 200704);
  unsigned short* Xb  = (unsigned short*)(ws + 266240);
  unsigned short* G   = (unsigned short*)(ws + 33820672);
  unsigned short* Wgt = (unsigned short*)(ws + 79958016);
  unsigned short* Wut = (unsigned short*)(ws + 126095360);
  unsigned short* Wdt = (unsigned short*)(ws + 172232704);
  unsigned short* Y   = (unsigned short*)(ws + 79958016);  // overlays Wgt/Wut (dead after gemm1)

  hipMemsetAsync(d_ws, 0, 4096, stream);

  router_kernel<<<T_TOK / 4, 256, 0, stream>>>(X, GW, topk_e, topk_p, counts, Xb);
  setup_kernel<<<1, 256, 0, stream>>>(counts, cursor, ntiles, tile_e, tile_b, tile_r);
  scatter_kernel<<<T_TOK / 256, 256, 0, stream>>>(topk_e, cursor, pair_tok, slot);
  transpose_cvt_kernel<<<dim3(I_DIM / 64, H_DIM / 64, N_EXP), 256, 0, stream>>>(Wg, Wgt, H_DIM, I_DIM);
  transpose_cvt_kernel<<<dim3(I_DIM / 64, H_DIM / 64, N_EXP), 256, 0, stream>>>(Wu, Wut, H_DIM, I_DIM);
  transpose_cvt_kernel<<<dim3(H_DIM / 64, I_DIM / 64, N_EXP), 256, 0, stream>>>(Wd, Wdt, I_DIM, H_DIM);

  // gemm1 split into two half-grid dispatches (diagnostic: surfaces gemm2/transposes in top-5)
  gemm1_kernel<<<dim3(I_DIM / 128, MAX_TILES / 2), 256, 0, stream>>>(
      Xb, Wgt, Wut, ntiles, tile_e, tile_b, tile_r, pair_tok, G, 0);
  gemm1_kernel<<<dim3(I_DIM / 128, MAX_TILES / 2), 256, 0, stream>>>(
      Xb, Wgt, Wut, ntiles, tile_e, tile_b, tile_r, pair_tok, G, MAX_TILES / 2);
  gemm2_kernel<<<dim3(H_DIM / 128, MAX_TILES), 256, 0, stream>>>(
      G, Wdt, ntiles, tile_e, tile_b, tile_r, Y);
  combine_kernel<<<T_TOK, 256, 0, stream>>>(Y, slot, topk_p, out);
}